// Round 12
// baseline (858.368 us; speedup 1.0000x reference)
//
#include <hip/hip_runtime.h>
#include <hip/hip_fp16.h>

#define N_FM 100000
#define N_TP 4096
#define N_SM 100000
#define HID 128
#define E_QOQ 1000000
#define E_BP 1000000
#define E_CP 500000
#define E_CD 500000
#define E_RB 1000000
#define E_TOT 4000000
#define TR 32

// global edge-id order: qoq | cp | rb | bp | cd
#define EO_CP  1000000
#define EO_RB  1500000
#define EO_BP  2500000
#define EO_CD  3500000

// element space (concatenated): qoq | cp | rb | bp | cd
#define EL_QOQ 0
#define EL_CP  (N_FM)
#define EL_RB  (2 * N_FM)
#define EL_BP  (3 * N_FM)
#define EL_CD  (3 * N_FM + N_TP)
#define NTOT   (3 * N_FM + N_TP + N_SM)

// buckets: qoq 128 elems (shift 7) | cp/rb/cd 256 (shift 8) | bp 32 (shift 5)
#define BB_QOQ 0
#define BB_CP  782
#define BB_RB  1173
#define BB_BP  1564
#define BB_CD  1692
#define NBUCK  2083
#define CHUNK  16384
#define NCHUNK ((E_TOT + CHUNK - 1) / CHUNK)

// fixed bucket capacities (>=6 sigma above Poisson mean: qoq/cp 1279, rb 2558, bp 7812, cd 1279)
#define PAIRS_CAP 5784064

__device__ __forceinline__ int bucket_base(int b) {
    if (b < BB_CP) return b * 2048;
    if (b < BB_RB) return 1601536 + (b - BB_CP) * 2048;
    if (b < BB_BP) return 2402304 + (b - BB_RB) * 3584;
    if (b < BB_CD) return 3803648 + (b - BB_BP) * 9216;
    return 4983296 + (b - BB_CD) * 2048;
}

typedef _Float16 h2 __attribute__((ext_vector_type(2)));

#if defined(__has_builtin)
#if __has_builtin(__builtin_amdgcn_fdot2)
#define HAVE_FDOT2 1
#endif
#endif

union U32H2 { unsigned u; h2 h; };

__device__ __forceinline__ unsigned pk2(float a, float b) {
    U32H2 x; x.h = h2{(_Float16)a, (_Float16)b}; return x.u;
}
__device__ __forceinline__ float dot2(float acc, unsigned a, unsigned b) {
    U32H2 x, y; x.u = a; y.u = b;
#ifdef HAVE_FDOT2
    return __builtin_amdgcn_fdot2(x.h, y.h, acc, false);
#else
    return acc + (float)x.h[0] * (float)y.h[0] + (float)x.h[1] * (float)y.h[1];
#endif
}

// ---------------------------------------------------------------- unified pack kernel
#define R1 (N_FM * 32)
#define R2 (R1 + N_SM * 16)
#define R3 (R2 + N_TP * 16)
#define R4 (R3 + 32 * HID)
#define R5 (R4 + 16 * HID)
#define R6 (R5 + 16 * HID)
#define R7 (R6 + 32 * HID)
#define R8 (R7 + 32 * HID)
#define R9 (R8 + 16 * HID)
#define R10 (R9 + 16 * HID)
#define R11 (R10 + 16 * HID)

__device__ __forceinline__ void pack_w_elem(const float* W, unsigned* dst, int j) {
    int rr = j >> 7, c = j & 127;
    dst[j] = pk2(W[(2 * rr) * HID + c], W[(2 * rr + 1) * HID + c]);
}

__global__ void pack_all(const float* __restrict__ x_fm, const float* __restrict__ x_sm,
                         const float* __restrict__ pe_table, const float* __restrict__ pvol,
                         const float* __restrict__ qoq_Wl, const float* __restrict__ cp_Wl,
                         const float* __restrict__ rb_Wl, const float* __restrict__ qoq_Wr,
                         const float* __restrict__ cp_Wr, const float* __restrict__ rb_Wr,
                         const float* __restrict__ bp_Wl, const float* __restrict__ bp_Wr,
                         const float* __restrict__ cd_Wl, const float* __restrict__ cd_Wr,
                         unsigned* __restrict__ x_fm_f, unsigned* __restrict__ x_sm_f,
                         unsigned* __restrict__ pe_f, unsigned* __restrict__ wf_fm,
                         unsigned* __restrict__ wf_tp, unsigned* __restrict__ wf_sm) {
    int gid = blockIdx.x * blockDim.x + threadIdx.x;
    if (gid < R1) {
        float2 t = ((const float2*)x_fm)[gid];
        x_fm_f[gid] = pk2(t.x, t.y);
    } else if (gid < R2) {
        int i = gid - R1;
        float2 t = ((const float2*)x_sm)[i];
        x_sm_f[i] = pk2(t.x, t.y);
    } else if (gid < R3) {
        int i = gid - R2;
        float2 t = ((const float2*)pe_table)[i];
        float v = pvol[i >> 4];
        pe_f[i] = pk2(t.x * v, t.y * v);
    } else if (gid < R4) {
        pack_w_elem(qoq_Wl, wf_fm, gid - R3);
    } else if (gid < R5) {
        pack_w_elem(cp_Wl, wf_fm + 32 * HID, gid - R4);
    } else if (gid < R6) {
        pack_w_elem(rb_Wl, wf_fm + 48 * HID, gid - R5);
    } else if (gid < R7) {
        int j = gid - R6;
        int rr = j >> 7, c = j & 127;
        float a0 = qoq_Wr[(2 * rr) * HID + c] + cp_Wr[(2 * rr) * HID + c] + rb_Wr[(2 * rr) * HID + c];
        float a1 = qoq_Wr[(2 * rr + 1) * HID + c] + cp_Wr[(2 * rr + 1) * HID + c] + rb_Wr[(2 * rr + 1) * HID + c];
        wf_fm[64 * HID + j] = pk2(a0, a1);
    } else if (gid < R8) {
        pack_w_elem(bp_Wl, wf_tp, gid - R7);
    } else if (gid < R9) {
        pack_w_elem(bp_Wr, wf_tp + 32 * HID, gid - R8);
    } else if (gid < R10) {
        pack_w_elem(cd_Wl, wf_sm, gid - R9);
    } else if (gid < R11) {
        pack_w_elem(cd_Wr, wf_sm + 16 * HID, gid - R10);
    }
}

// ---------------------------------------------------------------- edge decode
struct EdgePtrs {
    const int *qs, *qd, *cs, *cd_, *rs, *rd, *bs, *bd, *ds, *dd;
};

template <bool NEED_SRC>
__device__ __forceinline__ void edge_decode(const EdgePtrs& P, int e, int& bucket, int& dl, int& src) {
    if (e < EO_CP) {
        int d = P.qd[e]; bucket = BB_QOQ + (d >> 7); dl = d & 127;
        if (NEED_SRC) src = P.qs[e];
    } else if (e < EO_RB) {
        int i = e - EO_CP; int d = P.cd_[i]; bucket = BB_CP + (d >> 8); dl = d & 255;
        if (NEED_SRC) src = P.cs[i];
    } else if (e < EO_BP) {
        int i = e - EO_RB; int d = P.rd[i]; bucket = BB_RB + (d >> 8); dl = d & 255;
        if (NEED_SRC) src = P.rs[i];
    } else if (e < EO_CD) {
        int i = e - EO_BP; int d = P.bd[i]; bucket = BB_BP + (d >> 5); dl = d & 31;
        if (NEED_SRC) src = P.bs[i];
    } else {
        int i = e - EO_CD; int d = P.dd[i]; bucket = BB_CD + (d >> 8); dl = d & 255;
        if (NEED_SRC) src = P.ds[i];
    }
}

// ---------------------------------------------------------------- bin: block-reserved bucket scatter
// pairs[pos] = (dl << 24) | src ; buckets have fixed over-provisioned capacity (no hist/scan pass)
__global__ void __launch_bounds__(256) bin_kernel(EdgePtrs P, int* __restrict__ bwork,
                                                  unsigned* __restrict__ pairs) {
    __shared__ int lh[NBUCK];
    const int tid = threadIdx.x;
    for (int i = tid; i < NBUCK; i += 256) lh[i] = 0;
    __syncthreads();
    int base = blockIdx.x * CHUNK;
    int lim = min(base + CHUNK, E_TOT);
    for (int e = base + tid; e < lim; e += 256) {
        int b, dl, s;
        edge_decode<false>(P, e, b, dl, s);
        atomicAdd(&lh[b], 1);
    }
    __syncthreads();
    for (int b = tid; b < NBUCK; b += 256) {
        int c = lh[b];
        lh[b] = c ? bucket_base(b) + atomicAdd(&bwork[b], c) : 0;
    }
    __syncthreads();
    for (int e = base + tid; e < lim; e += 256) {
        int b, dl, s;
        edge_decode<true>(P, e, b, dl, s);
        int pos = atomicAdd(&lh[b], 1);
        pairs[pos] = ((unsigned)dl << 24) | (unsigned)s;
    }
}

// ---------------------------------------------------------------- esort: per-bucket LDS counting sort by element
// one block per bucket; emits element-sorted src (so) + per-element [beg,end)
__global__ void __launch_bounds__(256) esort(const int* __restrict__ bwork,
                                             const unsigned* __restrict__ pairs,
                                             int* __restrict__ so,
                                             int* __restrict__ el_beg, int* __restrict__ el_end) {
    __shared__ int hist[256], scn[256];
    const int b = blockIdx.x;
    const int tid = threadIdx.x;
    int beg = bucket_base(b);
    int end = beg + bwork[b];
    int egbase, ne;
    if (b < BB_CP)      { int e0 = (b - BB_QOQ) << 7; egbase = EL_QOQ + e0; ne = min(128, N_FM - e0); }
    else if (b < BB_RB) { int e0 = (b - BB_CP) << 8;  egbase = EL_CP + e0;  ne = min(256, N_FM - e0); }
    else if (b < BB_BP) { int e0 = (b - BB_RB) << 8;  egbase = EL_RB + e0;  ne = min(256, N_FM - e0); }
    else if (b < BB_CD) { int e0 = (b - BB_BP) << 5;  egbase = EL_BP + e0;  ne = min(32, N_TP - e0); }
    else                { int e0 = (b - BB_CD) << 8;  egbase = EL_CD + e0;  ne = min(256, N_SM - e0); }
    hist[tid] = 0;
    __syncthreads();
    for (int e = beg + tid; e < end; e += 256)
        atomicAdd(&hist[pairs[e] >> 24], 1);
    __syncthreads();
    int v = hist[tid];
    scn[tid] = v;
    __syncthreads();
    for (int off = 1; off < 256; off <<= 1) {
        int u = (tid >= off) ? scn[tid - off] : 0;
        __syncthreads();
        scn[tid] += u;
        __syncthreads();
    }
    int excl = scn[tid] - v;
    if (tid < ne) {
        el_beg[egbase + tid] = beg + excl;
        el_end[egbase + tid] = beg + excl + v;
    }
    hist[tid] = excl;  // cursor
    __syncthreads();
    for (int e = beg + tid; e < end; e += 256) {
        unsigned pr = pairs[e];
        int dl = pr >> 24;
        int pos = atomicAdd(&hist[dl], 1);
        so[beg + pos] = (int)(pr & 0xFFFFFF);
    }
}

// ---------------------------------------------------------------- gather: element CSR, register fp32 accumulate
template <int LOGP>
__device__ __forceinline__ void gather_one(int g, int lane, const int* __restrict__ begs,
                                           const int* __restrict__ ends,
                                           const int* __restrict__ ssrc,
                                           const unsigned* __restrict__ feat,
                                           unsigned* __restrict__ mean) {
    const int P = 1 << LOGP;
    int beg = begs[g], end = ends[g];
    float alo = 0.0f, ahi = 0.0f;
    int i = beg;
    for (; i + 4 <= end; i += 4) {
        int s0 = ssrc[i], s1 = ssrc[i + 1], s2 = ssrc[i + 2], s3 = ssrc[i + 3];
        unsigned v0 = feat[(size_t)s0 * P + lane];
        unsigned v1 = feat[(size_t)s1 * P + lane];
        unsigned v2 = feat[(size_t)s2 * P + lane];
        unsigned v3 = feat[(size_t)s3 * P + lane];
        U32H2 u;
        u.u = v0; alo += (float)u.h[0]; ahi += (float)u.h[1];
        u.u = v1; alo += (float)u.h[0]; ahi += (float)u.h[1];
        u.u = v2; alo += (float)u.h[0]; ahi += (float)u.h[1];
        u.u = v3; alo += (float)u.h[0]; ahi += (float)u.h[1];
    }
    for (; i < end; i++) {
        unsigned v = feat[(size_t)ssrc[i] * P + lane];
        U32H2 u; u.u = v;
        alo += (float)u.h[0]; ahi += (float)u.h[1];
    }
    float ic = (end > beg) ? 1.0f / (float)(end - beg) : 0.0f;
    mean[(size_t)g * P + lane] = pk2(alo * ic, ahi * ic);
}

#define G1 (N_TP * 32)
#define G2 (G1 + N_FM * 32)
#define G3 (G2 + N_FM * 16)
#define G4 (G3 + N_SM * 16)
#define G5 (G4 + N_FM * 16)

__global__ void gather_all(const int* __restrict__ el_beg, const int* __restrict__ el_end,
                           const int* __restrict__ so_all,
                           const unsigned* __restrict__ x_fm_f, const unsigned* __restrict__ pe_f,
                           unsigned* __restrict__ mean_qoq, unsigned* __restrict__ mean_cp,
                           unsigned* __restrict__ mean_rb, unsigned* __restrict__ mean_bp,
                           unsigned* __restrict__ mean_cd) {
    int gid = blockIdx.x * blockDim.x + threadIdx.x;
    if (gid < G1) {
        gather_one<5>(gid >> 5, gid & 31, el_beg + EL_BP, el_end + EL_BP, so_all, x_fm_f, mean_bp);
    } else if (gid < G2) {
        int i = gid - G1;
        gather_one<5>(i >> 5, i & 31, el_beg + EL_QOQ, el_end + EL_QOQ, so_all, x_fm_f, mean_qoq);
    } else if (gid < G3) {
        int i = gid - G2;
        gather_one<4>(i >> 4, i & 15, el_beg + EL_CP, el_end + EL_CP, so_all, pe_f, mean_cp);
    } else if (gid < G4) {
        int i = gid - G3;
        gather_one<4>(i >> 4, i & 15, el_beg + EL_CD, el_end + EL_CD, so_all, pe_f, mean_cd);
    } else if (gid < G5) {
        int i = gid - G4;
        gather_one<4>(i >> 4, i & 15, el_beg + EL_RB, el_end + EL_RB, so_all, pe_f, mean_rb);
    }
}

// ---------------------------------------------------------------- fm rows: 2 cols/thread (grid == ntiles)
__global__ void __launch_bounds__(128, 4)
fm_rows2(const unsigned* __restrict__ mean_qoq, const unsigned* __restrict__ mean_cp,
         const unsigned* __restrict__ mean_rb, const unsigned* __restrict__ x_fm_f,
         const unsigned* __restrict__ wf,
         const float* __restrict__ bl_q, const float* __restrict__ bl_c,
         const float* __restrict__ bl_r,
         const float* __restrict__ ln_g, const float* __restrict__ ln_b,
         float* __restrict__ colsum) {
    const int tid = threadIdx.x;
    const int lane = tid & 63, wave = tid >> 6;
    const int rbase = wave * 16;
    __shared__ __align__(16) unsigned s_in[TR][100];
    const float bias0 = bl_q[lane] + bl_c[lane] + bl_r[lane];
    const float bias1 = bl_q[lane + 64] + bl_c[lane + 64] + bl_r[lane + 64];
    const float g0 = ln_g[lane], b0 = ln_b[lane];
    const float g1 = ln_g[lane + 64], b1 = ln_b[lane + 64];
    float colacc0 = 0.0f, colacc1 = 0.0f;
    const int ntiles = N_FM / TR;
    for (int tile = blockIdx.x; tile < ntiles; tile += gridDim.x) {
        const size_t row0 = (size_t)tile * TR;
        for (int i = tid; i < TR * 8; i += 128) {
            int r = i >> 3;
            *(uint4*)&s_in[r][(i & 7) * 4] = ((const uint4*)mean_qoq)[row0 * 8 + i];
        }
        for (int i = tid; i < TR * 4; i += 128) {
            int r = i >> 2;
            *(uint4*)&s_in[r][32 + (i & 3) * 4] = ((const uint4*)mean_cp)[row0 * 4 + i];
        }
        for (int i = tid; i < TR * 4; i += 128) {
            int r = i >> 2;
            *(uint4*)&s_in[r][48 + (i & 3) * 4] = ((const uint4*)mean_rb)[row0 * 4 + i];
        }
        for (int i = tid; i < TR * 8; i += 128) {
            int r = i >> 3;
            *(uint4*)&s_in[r][64 + (i & 7) * 4] = ((const uint4*)x_fm_f)[row0 * 8 + i];
        }
        __syncthreads();
        float a0[16], a1[16];
#pragma unroll
        for (int r = 0; r < 16; r++) { a0[r] = 0.0f; a1[r] = 0.0f; }
        for (int p = 0; p < 96; p += 4) {
            unsigned w00 = wf[(p + 0) * HID + lane], w01 = wf[(p + 1) * HID + lane];
            unsigned w02 = wf[(p + 2) * HID + lane], w03 = wf[(p + 3) * HID + lane];
            unsigned w10 = wf[(p + 0) * HID + lane + 64], w11 = wf[(p + 1) * HID + lane + 64];
            unsigned w12 = wf[(p + 2) * HID + lane + 64], w13 = wf[(p + 3) * HID + lane + 64];
#pragma unroll
            for (int r = 0; r < 16; r++) {
                uint4 v = *(const uint4*)&s_in[rbase + r][p];
                a0[r] = dot2(dot2(dot2(dot2(a0[r], v.x, w00), v.y, w01), v.z, w02), v.w, w03);
                a1[r] = dot2(dot2(dot2(dot2(a1[r], v.x, w10), v.y, w11), v.z, w12), v.w, w13);
            }
        }
#pragma unroll
        for (int r = 0; r < 16; r++) {
            float y0 = (a0[r] + bias0) * (1.0f / 3.0f);
            float y1 = (a1[r] + bias1) * (1.0f / 3.0f);
            float s = y0 + y1, q = y0 * y0 + y1 * y1;
#pragma unroll
            for (int off = 1; off < 64; off <<= 1) {
                s += __shfl_xor(s, off);
                q += __shfl_xor(q, off);
            }
            float mu = s * (1.0f / 128.0f);
            float var = fmaxf(q * (1.0f / 128.0f) - mu * mu, 0.0f);
            float rs = rsqrtf(var + 1e-5f);
            colacc0 += fmaxf((y0 - mu) * rs * g0 + b0, 0.0f);
            colacc1 += fmaxf((y1 - mu) * rs * g1 + b1, 0.0f);
        }
        __syncthreads();
    }
    unsafeAtomicAdd(&colsum[lane], colacc0);
    unsafeAtomicAdd(&colsum[lane + 64], colacc1);
}

// ---------------------------------------------------------------- generic rows, 2 cols/thread
template <int PA, int PB>
__global__ void __launch_bounds__(128, 4)
rows2(int ntiles, const unsigned* __restrict__ meanA, const unsigned* __restrict__ xB,
      const unsigned* __restrict__ wf, const float* __restrict__ bl,
      const float* __restrict__ ln_g, const float* __restrict__ ln_b,
      float* __restrict__ colsum) {
    const int tid = threadIdx.x;
    const int lane = tid & 63, wave = tid >> 6;
    const int rbase = wave * 16;
    __shared__ __align__(16) unsigned s_in[TR][PA + PB + 4];
    const float bias0 = bl[lane], bias1 = bl[lane + 64];
    const float g0 = ln_g[lane], b0 = ln_b[lane];
    const float g1 = ln_g[lane + 64], b1 = ln_b[lane + 64];
    float colacc0 = 0.0f, colacc1 = 0.0f;
    const int A4 = PA / 4, B4 = PB / 4;
    for (int tile = blockIdx.x; tile < ntiles; tile += gridDim.x) {
        const size_t row0 = (size_t)tile * TR;
        for (int i = tid; i < TR * A4; i += 128) {
            int r = i / A4, q = i % A4;
            *(uint4*)&s_in[r][q * 4] = ((const uint4*)meanA)[row0 * A4 + i];
        }
        for (int i = tid; i < TR * B4; i += 128) {
            int r = i / B4, q = i % B4;
            *(uint4*)&s_in[r][PA + q * 4] = ((const uint4*)xB)[row0 * B4 + i];
        }
        __syncthreads();
        float a0[16], a1[16];
#pragma unroll
        for (int r = 0; r < 16; r++) { a0[r] = 0.0f; a1[r] = 0.0f; }
        for (int p = 0; p < PA + PB; p += 4) {
            unsigned w00 = wf[(p + 0) * HID + lane], w01 = wf[(p + 1) * HID + lane];
            unsigned w02 = wf[(p + 2) * HID + lane], w03 = wf[(p + 3) * HID + lane];
            unsigned w10 = wf[(p + 0) * HID + lane + 64], w11 = wf[(p + 1) * HID + lane + 64];
            unsigned w12 = wf[(p + 2) * HID + lane + 64], w13 = wf[(p + 3) * HID + lane + 64];
#pragma unroll
            for (int r = 0; r < 16; r++) {
                uint4 v = *(const uint4*)&s_in[rbase + r][p];
                a0[r] = dot2(dot2(dot2(dot2(a0[r], v.x, w00), v.y, w01), v.z, w02), v.w, w03);
                a1[r] = dot2(dot2(dot2(dot2(a1[r], v.x, w10), v.y, w11), v.z, w12), v.w, w13);
            }
        }
#pragma unroll
        for (int r = 0; r < 16; r++) {
            float y0 = a0[r] + bias0;
            float y1 = a1[r] + bias1;
            float s = y0 + y1, q = y0 * y0 + y1 * y1;
#pragma unroll
            for (int off = 1; off < 64; off <<= 1) {
                s += __shfl_xor(s, off);
                q += __shfl_xor(q, off);
            }
            float mu = s * (1.0f / 128.0f);
            float var = fmaxf(q * (1.0f / 128.0f) - mu * mu, 0.0f);
            float rs = rsqrtf(var + 1e-5f);
            colacc0 += fmaxf((y0 - mu) * rs * g0 + b0, 0.0f);
            colacc1 += fmaxf((y1 - mu) * rs * g1 + b1, 0.0f);
        }
        __syncthreads();
    }
    unsafeAtomicAdd(&colsum[lane], colacc0);
    unsafeAtomicAdd(&colsum[lane + 64], colacc1);
}

// ---------------------------------------------------------------- head MLP -> scalar (split-K)
__global__ void head_kernel(const float* __restrict__ colsum, const float* __restrict__ gf,
                            const float* __restrict__ W1, const float* __restrict__ b1,
                            const float* __restrict__ W2, const float* __restrict__ b2,
                            float* __restrict__ out) {
    __shared__ float h[448];
    __shared__ float sh[512];
    __shared__ float h1[64];
    int t = threadIdx.x;  // 512 threads
    if (t < 128) h[t] = colsum[t] * (1.0f / N_FM);
    else if (t < 256) h[t] = colsum[t] * (1.0f / N_TP);
    else if (t < 384) h[t] = colsum[t] * (1.0f / N_SM);
    else if (t < 448) h[t] = gf[t - 384];
    __syncthreads();
    {
        int col = t & 63, slice = t >> 6;
        float a = 0.0f;
        for (int k = slice * 56; k < slice * 56 + 56; k++) a += h[k] * W1[k * 64 + col];
        sh[slice * 64 + col] = a;
    }
    __syncthreads();
    if (t < 64) {
        float a = b1[t];
#pragma unroll
        for (int s = 0; s < 8; s++) a += sh[s * 64 + t];
        h1[t] = fmaxf(a, 0.0f);
    }
    __syncthreads();
    if (t < 64) {
        float p = h1[t] * W2[t];
#pragma unroll
        for (int off = 1; off < 64; off <<= 1) p += __shfl_xor(p, off);
        if (t == 0) out[0] = p + b2[0];
    }
}

extern "C" void kernel_launch(void* const* d_in, const int* in_sizes, int n_in,
                              void* d_out, int out_size, void* d_ws, size_t ws_size,
                              hipStream_t stream) {
    const float* x_fm = (const float*)d_in[0];
    const float* x_sm = (const float*)d_in[1];
    const float* period_vol = (const float*)d_in[2];
    const float* gf = (const float*)d_in[3];
    const float* pe_table = (const float*)d_in[4];
    const int* qoq_src = (const int*)d_in[5];
    const int* qoq_dst = (const int*)d_in[6];
    const int* bp_src = (const int*)d_in[7];
    const int* bp_dst = (const int*)d_in[8];
    const int* cp_src = (const int*)d_in[9];
    const int* cp_dst = (const int*)d_in[10];
    const int* cd_src = (const int*)d_in[11];
    const int* cd_dst = (const int*)d_in[12];
    const int* rb_src = (const int*)d_in[13];
    const int* rb_dst = (const int*)d_in[14];
    const float* qoq_Wl = (const float*)d_in[15];
    const float* qoq_bl = (const float*)d_in[16];
    const float* qoq_Wr = (const float*)d_in[17];
    const float* bp_Wl = (const float*)d_in[18];
    const float* bp_bl = (const float*)d_in[19];
    const float* bp_Wr = (const float*)d_in[20];
    const float* cp_Wl = (const float*)d_in[21];
    const float* cp_bl = (const float*)d_in[22];
    const float* cp_Wr = (const float*)d_in[23];
    const float* cd_Wl = (const float*)d_in[24];
    const float* cd_bl = (const float*)d_in[25];
    const float* cd_Wr = (const float*)d_in[26];
    const float* rb_Wl = (const float*)d_in[27];
    const float* rb_bl = (const float*)d_in[28];
    const float* rb_Wr = (const float*)d_in[29];
    const float* ln_fm_g = (const float*)d_in[30];
    const float* ln_fm_b = (const float*)d_in[31];
    const float* ln_tp_g = (const float*)d_in[32];
    const float* ln_tp_b = (const float*)d_in[33];
    const float* ln_sm_g = (const float*)d_in[34];
    const float* ln_sm_b = (const float*)d_in[35];
    const float* head_W1 = (const float*)d_in[36];
    const float* head_b1 = (const float*)d_in[37];
    const float* head_W2 = (const float*)d_in[38];
    const float* head_b2 = (const float*)d_in[39];

    // workspace (4-byte words); zero region: bucket cursors + colsum
    unsigned* wsu = (unsigned*)d_ws;
    size_t off = 0;
    int* bwork = (int*)(wsu + off); off += NBUCK;
    float* colsum = (float*)(wsu + off); off += 384;
    size_t zero_words = off;
    unsigned* pairs = wsu + off; off += PAIRS_CAP;
    int* so_all = (int*)(wsu + off); off += PAIRS_CAP;
    int* el_beg = (int*)(wsu + off); off += NTOT;
    int* el_end = (int*)(wsu + off); off += NTOT;
    unsigned* mean_qoq = wsu + off; off += (size_t)N_FM * 32;
    unsigned* mean_cp  = wsu + off; off += (size_t)N_FM * 16;
    unsigned* mean_rb  = wsu + off; off += (size_t)N_FM * 16;
    unsigned* mean_bp  = wsu + off; off += (size_t)N_TP * 32;
    unsigned* mean_cd  = wsu + off; off += (size_t)N_SM * 16;
    unsigned* pe_f     = wsu + off; off += (size_t)N_TP * 16;
    unsigned* x_fm_f   = wsu + off; off += (size_t)N_FM * 32;
    unsigned* x_sm_f   = wsu + off; off += (size_t)N_SM * 16;
    unsigned* wf_fm    = wsu + off; off += 96 * HID;
    unsigned* wf_tp    = wsu + off; off += 48 * HID;
    unsigned* wf_sm    = wsu + off; off += 32 * HID;

    hipMemsetAsync(d_ws, 0, zero_words * 4, stream);

    pack_all<<<(R11 + 255) / 256, 256, 0, stream>>>(
        x_fm, x_sm, pe_table, period_vol, qoq_Wl, cp_Wl, rb_Wl, qoq_Wr, cp_Wr, rb_Wr,
        bp_Wl, bp_Wr, cd_Wl, cd_Wr, x_fm_f, x_sm_f, pe_f, wf_fm, wf_tp, wf_sm);

    EdgePtrs EP{qoq_src, qoq_dst, cp_src, cp_dst, rb_src, rb_dst, bp_src, bp_dst, cd_src, cd_dst};

    bin_kernel<<<NCHUNK, 256, 0, stream>>>(EP, bwork, pairs);
    esort<<<NBUCK, 256, 0, stream>>>(bwork, pairs, so_all, el_beg, el_end);
    gather_all<<<(G5 + 255) / 256, 256, 0, stream>>>(el_beg, el_end, so_all, x_fm_f, pe_f,
                                                     mean_qoq, mean_cp, mean_rb, mean_bp, mean_cd);

    fm_rows2<<<N_FM / TR, 128, 0, stream>>>(mean_qoq, mean_cp, mean_rb, x_fm_f, wf_fm,
                                            qoq_bl, cp_bl, rb_bl, ln_fm_g, ln_fm_b, colsum);
    rows2<32, 16><<<N_TP / TR, 128, 0, stream>>>(N_TP / TR, mean_bp, pe_f, wf_tp,
                                                 bp_bl, ln_tp_g, ln_tp_b, colsum + 128);
    rows2<16, 16><<<N_SM / TR, 128, 0, stream>>>(N_SM / TR, mean_cd, x_sm_f, wf_sm,
                                                 cd_bl, ln_sm_g, ln_sm_b, colsum + 256);

    head_kernel<<<1, 512, 0, stream>>>(colsum, gf, head_W1, head_b1, head_W2, head_b2,
                                       (float*)d_out);
}

// Round 13
// 771.068 us; speedup vs baseline: 1.1132x; 1.1132x over previous
//
#include <hip/hip_runtime.h>
#include <hip/hip_fp16.h>

#define N_FM 100000
#define N_TP 4096
#define N_SM 100000
#define HID 128
#define E_QOQ 1000000
#define E_BP 1000000
#define E_CP 500000
#define E_CD 500000
#define E_RB 1000000
#define E_TOT 4000000
#define TR 32

// global edge-id order: qoq | cp | rb | bp | cd
#define EO_CP  1000000
#define EO_RB  1500000
#define EO_BP  2500000
#define EO_CD  3500000

// element space (concatenated): qoq | cp | rb | bp | cd
#define EL_QOQ 0
#define EL_CP  (N_FM)
#define EL_RB  (2 * N_FM)
#define EL_BP  (3 * N_FM)
#define EL_CD  (3 * N_FM + N_TP)
#define NTOT   (3 * N_FM + N_TP + N_SM)

// buckets: qoq 128 elems (shift 7) | cp/rb/cd 256 (shift 8) | bp 32 (shift 5)
#define BB_QOQ 0
#define BB_CP  782
#define BB_RB  1173
#define BB_BP  1564
#define BB_CD  1692
#define NBUCK  2083
#define CHUNK  16384
#define NCHUNK ((E_TOT + CHUNK - 1) / CHUNK)

#define PAIRS_CAP 5784064

__device__ __forceinline__ int bucket_base(int b) {
    if (b < BB_CP) return b * 2048;
    if (b < BB_RB) return 1601536 + (b - BB_CP) * 2048;
    if (b < BB_BP) return 2402304 + (b - BB_RB) * 3584;
    if (b < BB_CD) return 3803648 + (b - BB_BP) * 9216;
    return 4983296 + (b - BB_CD) * 2048;
}

typedef _Float16 h2 __attribute__((ext_vector_type(2)));

#if defined(__has_builtin)
#if __has_builtin(__builtin_amdgcn_fdot2)
#define HAVE_FDOT2 1
#endif
#endif

union U32H2 { unsigned u; h2 h; };

__device__ __forceinline__ unsigned pk2(float a, float b) {
    U32H2 x; x.h = h2{(_Float16)a, (_Float16)b}; return x.u;
}
__device__ __forceinline__ float dot2(float acc, unsigned a, unsigned b) {
    U32H2 x, y; x.u = a; y.u = b;
#ifdef HAVE_FDOT2
    return __builtin_amdgcn_fdot2(x.h, y.h, acc, false);
#else
    return acc + (float)x.h[0] * (float)y.h[0] + (float)x.h[1] * (float)y.h[1];
#endif
}

// ---------------------------------------------------------------- unified pack kernel
#define R1 (N_FM * 32)
#define R2 (R1 + N_SM * 16)
#define R3 (R2 + N_TP * 16)
#define R4 (R3 + 32 * HID)
#define R5 (R4 + 16 * HID)
#define R6 (R5 + 16 * HID)
#define R7 (R6 + 32 * HID)
#define R8 (R7 + 32 * HID)
#define R9 (R8 + 16 * HID)
#define R10 (R9 + 16 * HID)
#define R11 (R10 + 16 * HID)

__device__ __forceinline__ void pack_w_elem(const float* W, unsigned* dst, int j) {
    int rr = j >> 7, c = j & 127;
    dst[j] = pk2(W[(2 * rr) * HID + c], W[(2 * rr + 1) * HID + c]);
}

__global__ void pack_all(const float* __restrict__ x_fm, const float* __restrict__ x_sm,
                         const float* __restrict__ pe_table, const float* __restrict__ pvol,
                         const float* __restrict__ qoq_Wl, const float* __restrict__ cp_Wl,
                         const float* __restrict__ rb_Wl, const float* __restrict__ qoq_Wr,
                         const float* __restrict__ cp_Wr, const float* __restrict__ rb_Wr,
                         const float* __restrict__ bp_Wl, const float* __restrict__ bp_Wr,
                         const float* __restrict__ cd_Wl, const float* __restrict__ cd_Wr,
                         unsigned* __restrict__ x_fm_f, unsigned* __restrict__ x_sm_f,
                         unsigned* __restrict__ pe_f, unsigned* __restrict__ wf_fm,
                         unsigned* __restrict__ wf_tp, unsigned* __restrict__ wf_sm) {
    int gid = blockIdx.x * blockDim.x + threadIdx.x;
    if (gid < R1) {
        float2 t = ((const float2*)x_fm)[gid];
        x_fm_f[gid] = pk2(t.x, t.y);
    } else if (gid < R2) {
        int i = gid - R1;
        float2 t = ((const float2*)x_sm)[i];
        x_sm_f[i] = pk2(t.x, t.y);
    } else if (gid < R3) {
        int i = gid - R2;
        float2 t = ((const float2*)pe_table)[i];
        float v = pvol[i >> 4];
        pe_f[i] = pk2(t.x * v, t.y * v);
    } else if (gid < R4) {
        pack_w_elem(qoq_Wl, wf_fm, gid - R3);
    } else if (gid < R5) {
        pack_w_elem(cp_Wl, wf_fm + 32 * HID, gid - R4);
    } else if (gid < R6) {
        pack_w_elem(rb_Wl, wf_fm + 48 * HID, gid - R5);
    } else if (gid < R7) {
        int j = gid - R6;
        int rr = j >> 7, c = j & 127;
        float a0 = qoq_Wr[(2 * rr) * HID + c] + cp_Wr[(2 * rr) * HID + c] + rb_Wr[(2 * rr) * HID + c];
        float a1 = qoq_Wr[(2 * rr + 1) * HID + c] + cp_Wr[(2 * rr + 1) * HID + c] + rb_Wr[(2 * rr + 1) * HID + c];
        wf_fm[64 * HID + j] = pk2(a0, a1);
    } else if (gid < R8) {
        pack_w_elem(bp_Wl, wf_tp, gid - R7);
    } else if (gid < R9) {
        pack_w_elem(bp_Wr, wf_tp + 32 * HID, gid - R8);
    } else if (gid < R10) {
        pack_w_elem(cd_Wl, wf_sm, gid - R9);
    } else if (gid < R11) {
        pack_w_elem(cd_Wr, wf_sm + 16 * HID, gid - R10);
    }
}

// ---------------------------------------------------------------- edge decode
struct EdgePtrs {
    const int *qs, *qd, *cs, *cd_, *rs, *rd, *bs, *bd, *ds, *dd;
};

template <bool NEED_SRC>
__device__ __forceinline__ void edge_decode(const EdgePtrs& P, int e, int& bucket, int& dl, int& src) {
    if (e < EO_CP) {
        int d = P.qd[e]; bucket = BB_QOQ + (d >> 7); dl = d & 127;
        if (NEED_SRC) src = P.qs[e];
    } else if (e < EO_RB) {
        int i = e - EO_CP; int d = P.cd_[i]; bucket = BB_CP + (d >> 8); dl = d & 255;
        if (NEED_SRC) src = P.cs[i];
    } else if (e < EO_BP) {
        int i = e - EO_RB; int d = P.rd[i]; bucket = BB_RB + (d >> 8); dl = d & 255;
        if (NEED_SRC) src = P.rs[i];
    } else if (e < EO_CD) {
        int i = e - EO_BP; int d = P.bd[i]; bucket = BB_BP + (d >> 5); dl = d & 31;
        if (NEED_SRC) src = P.bs[i];
    } else {
        int i = e - EO_CD; int d = P.dd[i]; bucket = BB_CD + (d >> 8); dl = d & 255;
        if (NEED_SRC) src = P.ds[i];
    }
}

// ---------------------------------------------------------------- bin: block-reserved bucket scatter
__global__ void __launch_bounds__(256) bin_kernel(EdgePtrs P, int* __restrict__ bwork,
                                                  unsigned* __restrict__ pairs) {
    __shared__ int lh[NBUCK];
    const int tid = threadIdx.x;
    for (int i = tid; i < NBUCK; i += 256) lh[i] = 0;
    __syncthreads();
    int base = blockIdx.x * CHUNK;
    int lim = min(base + CHUNK, E_TOT);
    for (int e = base + tid; e < lim; e += 256) {
        int b, dl, s;
        edge_decode<false>(P, e, b, dl, s);
        atomicAdd(&lh[b], 1);
    }
    __syncthreads();
    for (int b = tid; b < NBUCK; b += 256) {
        int c = lh[b];
        lh[b] = c ? bucket_base(b) + atomicAdd(&bwork[b], c) : 0;
    }
    __syncthreads();
    for (int e = base + tid; e < lim; e += 256) {
        int b, dl, s;
        edge_decode<true>(P, e, b, dl, s);
        int pos = atomicAdd(&lh[b], 1);
        pairs[pos] = ((unsigned)dl << 24) | (unsigned)s;
    }
}

// ---------------------------------------------------------------- esort: per-bucket LDS counting sort by element
__global__ void __launch_bounds__(256) esort(const int* __restrict__ bwork,
                                             const unsigned* __restrict__ pairs,
                                             int* __restrict__ so,
                                             int* __restrict__ el_beg, int* __restrict__ el_end) {
    __shared__ int hist[256], scn[256];
    const int b = blockIdx.x;
    const int tid = threadIdx.x;
    int beg = bucket_base(b);
    int end = beg + bwork[b];
    int egbase, ne;
    if (b < BB_CP)      { int e0 = (b - BB_QOQ) << 7; egbase = EL_QOQ + e0; ne = min(128, N_FM - e0); }
    else if (b < BB_RB) { int e0 = (b - BB_CP) << 8;  egbase = EL_CP + e0;  ne = min(256, N_FM - e0); }
    else if (b < BB_BP) { int e0 = (b - BB_RB) << 8;  egbase = EL_RB + e0;  ne = min(256, N_FM - e0); }
    else if (b < BB_CD) { int e0 = (b - BB_BP) << 5;  egbase = EL_BP + e0;  ne = min(32, N_TP - e0); }
    else                { int e0 = (b - BB_CD) << 8;  egbase = EL_CD + e0;  ne = min(256, N_SM - e0); }
    hist[tid] = 0;
    __syncthreads();
    for (int e = beg + tid; e < end; e += 256)
        atomicAdd(&hist[pairs[e] >> 24], 1);
    __syncthreads();
    int v = hist[tid];
    scn[tid] = v;
    __syncthreads();
    for (int off = 1; off < 256; off <<= 1) {
        int u = (tid >= off) ? scn[tid - off] : 0;
        __syncthreads();
        scn[tid] += u;
        __syncthreads();
    }
    int excl = scn[tid] - v;
    if (tid < ne) {
        el_beg[egbase + tid] = beg + excl;
        el_end[egbase + tid] = beg + excl + v;
    }
    hist[tid] = excl;  // cursor
    __syncthreads();
    for (int e = beg + tid; e < end; e += 256) {
        unsigned pr = pairs[e];
        int dl = pr >> 24;
        int pos = atomicAdd(&hist[dl], 1);
        so[beg + pos] = (int)(pr & 0xFFFFFF);
    }
}

// ---------------------------------------------------------------- gather: element CSR, register fp32 accumulate
template <int LOGP>
__device__ __forceinline__ void gather_one(int g, int lane, const int* __restrict__ begs,
                                           const int* __restrict__ ends,
                                           const int* __restrict__ ssrc,
                                           const unsigned* __restrict__ feat,
                                           unsigned* __restrict__ mean) {
    const int P = 1 << LOGP;
    int beg = begs[g], end = ends[g];
    float alo = 0.0f, ahi = 0.0f;
    int i = beg;
    for (; i + 4 <= end; i += 4) {
        int s0 = ssrc[i], s1 = ssrc[i + 1], s2 = ssrc[i + 2], s3 = ssrc[i + 3];
        unsigned v0 = feat[(size_t)s0 * P + lane];
        unsigned v1 = feat[(size_t)s1 * P + lane];
        unsigned v2 = feat[(size_t)s2 * P + lane];
        unsigned v3 = feat[(size_t)s3 * P + lane];
        U32H2 u;
        u.u = v0; alo += (float)u.h[0]; ahi += (float)u.h[1];
        u.u = v1; alo += (float)u.h[0]; ahi += (float)u.h[1];
        u.u = v2; alo += (float)u.h[0]; ahi += (float)u.h[1];
        u.u = v3; alo += (float)u.h[0]; ahi += (float)u.h[1];
    }
    for (; i < end; i++) {
        unsigned v = feat[(size_t)ssrc[i] * P + lane];
        U32H2 u; u.u = v;
        alo += (float)u.h[0]; ahi += (float)u.h[1];
    }
    float ic = (end > beg) ? 1.0f / (float)(end - beg) : 0.0f;
    mean[(size_t)g * P + lane] = pk2(alo * ic, ahi * ic);
}

#define G1 (N_TP * 32)
#define G2 (G1 + N_FM * 32)
#define G3 (G2 + N_FM * 16)
#define G4 (G3 + N_SM * 16)
#define G5 (G4 + N_FM * 16)

__global__ void gather_all(const int* __restrict__ el_beg, const int* __restrict__ el_end,
                           const int* __restrict__ so_all,
                           const unsigned* __restrict__ x_fm_f, const unsigned* __restrict__ pe_f,
                           unsigned* __restrict__ mean_qoq, unsigned* __restrict__ mean_cp,
                           unsigned* __restrict__ mean_rb, unsigned* __restrict__ mean_bp,
                           unsigned* __restrict__ mean_cd) {
    int gid = blockIdx.x * blockDim.x + threadIdx.x;
    if (gid < G1) {
        gather_one<5>(gid >> 5, gid & 31, el_beg + EL_BP, el_end + EL_BP, so_all, x_fm_f, mean_bp);
    } else if (gid < G2) {
        int i = gid - G1;
        gather_one<5>(i >> 5, i & 31, el_beg + EL_QOQ, el_end + EL_QOQ, so_all, x_fm_f, mean_qoq);
    } else if (gid < G3) {
        int i = gid - G2;
        gather_one<4>(i >> 4, i & 15, el_beg + EL_CP, el_end + EL_CP, so_all, pe_f, mean_cp);
    } else if (gid < G4) {
        int i = gid - G3;
        gather_one<4>(i >> 4, i & 15, el_beg + EL_CD, el_end + EL_CD, so_all, pe_f, mean_cd);
    } else if (gid < G5) {
        int i = gid - G4;
        gather_one<4>(i >> 4, i & 15, el_beg + EL_RB, el_end + EL_RB, so_all, pe_f, mean_rb);
    }
}

// ---------------------------------------------------------------- fm rows: 2 cols/thread, weights in registers
// 192 weight VGPRs/thread (fully-unrolled indexed arrays -> register file); launch_bounds(128,2) caps 256
__global__ void __launch_bounds__(128, 2)
fm_rows2(const unsigned* __restrict__ mean_qoq, const unsigned* __restrict__ mean_cp,
         const unsigned* __restrict__ mean_rb, const unsigned* __restrict__ x_fm_f,
         const unsigned* __restrict__ wf,
         const float* __restrict__ bl_q, const float* __restrict__ bl_c,
         const float* __restrict__ bl_r,
         const float* __restrict__ ln_g, const float* __restrict__ ln_b,
         float* __restrict__ colsum) {
    const int tid = threadIdx.x;
    const int lane = tid & 63, wave = tid >> 6;
    const int rbase = wave * 16;
    __shared__ __align__(16) unsigned s_in[TR][100];
    unsigned w0[96], w1[96];
#pragma unroll
    for (int p = 0; p < 96; p++) {
        w0[p] = wf[p * HID + lane];
        w1[p] = wf[p * HID + lane + 64];
    }
    const float bias0 = bl_q[lane] + bl_c[lane] + bl_r[lane];
    const float bias1 = bl_q[lane + 64] + bl_c[lane + 64] + bl_r[lane + 64];
    const float g0 = ln_g[lane], b0 = ln_b[lane];
    const float g1 = ln_g[lane + 64], b1 = ln_b[lane + 64];
    float colacc0 = 0.0f, colacc1 = 0.0f;
    const int ntiles = N_FM / TR;
    for (int tile = blockIdx.x; tile < ntiles; tile += gridDim.x) {
        const size_t row0 = (size_t)tile * TR;
        for (int i = tid; i < TR * 8; i += 128) {
            int r = i >> 3;
            *(uint4*)&s_in[r][(i & 7) * 4] = ((const uint4*)mean_qoq)[row0 * 8 + i];
        }
        for (int i = tid; i < TR * 4; i += 128) {
            int r = i >> 2;
            *(uint4*)&s_in[r][32 + (i & 3) * 4] = ((const uint4*)mean_cp)[row0 * 4 + i];
        }
        for (int i = tid; i < TR * 4; i += 128) {
            int r = i >> 2;
            *(uint4*)&s_in[r][48 + (i & 3) * 4] = ((const uint4*)mean_rb)[row0 * 4 + i];
        }
        for (int i = tid; i < TR * 8; i += 128) {
            int r = i >> 3;
            *(uint4*)&s_in[r][64 + (i & 7) * 4] = ((const uint4*)x_fm_f)[row0 * 8 + i];
        }
        __syncthreads();
        float a0[16], a1[16];
#pragma unroll
        for (int r = 0; r < 16; r++) { a0[r] = 0.0f; a1[r] = 0.0f; }
#pragma unroll
        for (int p = 0; p < 96; p += 4) {
#pragma unroll
            for (int r = 0; r < 16; r++) {
                uint4 v = *(const uint4*)&s_in[rbase + r][p];
                a0[r] = dot2(dot2(dot2(dot2(a0[r], v.x, w0[p]), v.y, w0[p + 1]), v.z, w0[p + 2]), v.w, w0[p + 3]);
                a1[r] = dot2(dot2(dot2(dot2(a1[r], v.x, w1[p]), v.y, w1[p + 1]), v.z, w1[p + 2]), v.w, w1[p + 3]);
            }
        }
#pragma unroll
        for (int r = 0; r < 16; r++) {
            float y0 = (a0[r] + bias0) * (1.0f / 3.0f);
            float y1 = (a1[r] + bias1) * (1.0f / 3.0f);
            float s = y0 + y1, q = y0 * y0 + y1 * y1;
#pragma unroll
            for (int off = 1; off < 64; off <<= 1) {
                s += __shfl_xor(s, off);
                q += __shfl_xor(q, off);
            }
            float mu = s * (1.0f / 128.0f);
            float var = fmaxf(q * (1.0f / 128.0f) - mu * mu, 0.0f);
            float rs = rsqrtf(var + 1e-5f);
            colacc0 += fmaxf((y0 - mu) * rs * g0 + b0, 0.0f);
            colacc1 += fmaxf((y1 - mu) * rs * g1 + b1, 0.0f);
        }
        __syncthreads();
    }
    unsafeAtomicAdd(&colsum[lane], colacc0);
    unsafeAtomicAdd(&colsum[lane + 64], colacc1);
}

// ---------------------------------------------------------------- generic rows, 2 cols/thread, weights in regs
template <int PA, int PB>
__global__ void __launch_bounds__(128, 3)
rows2(int ntiles, const unsigned* __restrict__ meanA, const unsigned* __restrict__ xB,
      const unsigned* __restrict__ wf, const float* __restrict__ bl,
      const float* __restrict__ ln_g, const float* __restrict__ ln_b,
      float* __restrict__ colsum) {
    const int tid = threadIdx.x;
    const int lane = tid & 63, wave = tid >> 6;
    const int rbase = wave * 16;
    __shared__ __align__(16) unsigned s_in[TR][PA + PB + 4];
    unsigned w0[PA + PB], w1[PA + PB];
#pragma unroll
    for (int p = 0; p < PA + PB; p++) {
        w0[p] = wf[p * HID + lane];
        w1[p] = wf[p * HID + lane + 64];
    }
    const float bias0 = bl[lane], bias1 = bl[lane + 64];
    const float g0 = ln_g[lane], b0 = ln_b[lane];
    const float g1 = ln_g[lane + 64], b1 = ln_b[lane + 64];
    float colacc0 = 0.0f, colacc1 = 0.0f;
    const int A4 = PA / 4, B4 = PB / 4;
    for (int tile = blockIdx.x; tile < ntiles; tile += gridDim.x) {
        const size_t row0 = (size_t)tile * TR;
        for (int i = tid; i < TR * A4; i += 128) {
            int r = i / A4, q = i % A4;
            *(uint4*)&s_in[r][q * 4] = ((const uint4*)meanA)[row0 * A4 + i];
        }
        for (int i = tid; i < TR * B4; i += 128) {
            int r = i / B4, q = i % B4;
            *(uint4*)&s_in[r][PA + q * 4] = ((const uint4*)xB)[row0 * B4 + i];
        }
        __syncthreads();
        float a0[16], a1[16];
#pragma unroll
        for (int r = 0; r < 16; r++) { a0[r] = 0.0f; a1[r] = 0.0f; }
#pragma unroll
        for (int p = 0; p < PA + PB; p += 4) {
#pragma unroll
            for (int r = 0; r < 16; r++) {
                uint4 v = *(const uint4*)&s_in[rbase + r][p];
                a0[r] = dot2(dot2(dot2(dot2(a0[r], v.x, w0[p]), v.y, w0[p + 1]), v.z, w0[p + 2]), v.w, w0[p + 3]);
                a1[r] = dot2(dot2(dot2(dot2(a1[r], v.x, w1[p]), v.y, w1[p + 1]), v.z, w1[p + 2]), v.w, w1[p + 3]);
            }
        }
#pragma unroll
        for (int r = 0; r < 16; r++) {
            float y0 = a0[r] + bias0;
            float y1 = a1[r] + bias1;
            float s = y0 + y1, q = y0 * y0 + y1 * y1;
#pragma unroll
            for (int off = 1; off < 64; off <<= 1) {
                s += __shfl_xor(s, off);
                q += __shfl_xor(q, off);
            }
            float mu = s * (1.0f / 128.0f);
            float var = fmaxf(q * (1.0f / 128.0f) - mu * mu, 0.0f);
            float rs = rsqrtf(var + 1e-5f);
            colacc0 += fmaxf((y0 - mu) * rs * g0 + b0, 0.0f);
            colacc1 += fmaxf((y1 - mu) * rs * g1 + b1, 0.0f);
        }
        __syncthreads();
    }
    unsafeAtomicAdd(&colsum[lane], colacc0);
    unsafeAtomicAdd(&colsum[lane + 64], colacc1);
}

// ---------------------------------------------------------------- head MLP -> scalar (split-K)
__global__ void head_kernel(const float* __restrict__ colsum, const float* __restrict__ gf,
                            const float* __restrict__ W1, const float* __restrict__ b1,
                            const float* __restrict__ W2, const float* __restrict__ b2,
                            float* __restrict__ out) {
    __shared__ float h[448];
    __shared__ float sh[512];
    __shared__ float h1[64];
    int t = threadIdx.x;  // 512 threads
    if (t < 128) h[t] = colsum[t] * (1.0f / N_FM);
    else if (t < 256) h[t] = colsum[t] * (1.0f / N_TP);
    else if (t < 384) h[t] = colsum[t] * (1.0f / N_SM);
    else if (t < 448) h[t] = gf[t - 384];
    __syncthreads();
    {
        int col = t & 63, slice = t >> 6;
        float a = 0.0f;
        for (int k = slice * 56; k < slice * 56 + 56; k++) a += h[k] * W1[k * 64 + col];
        sh[slice * 64 + col] = a;
    }
    __syncthreads();
    if (t < 64) {
        float a = b1[t];
#pragma unroll
        for (int s = 0; s < 8; s++) a += sh[s * 64 + t];
        h1[t] = fmaxf(a, 0.0f);
    }
    __syncthreads();
    if (t < 64) {
        float p = h1[t] * W2[t];
#pragma unroll
        for (int off = 1; off < 64; off <<= 1) p += __shfl_xor(p, off);
        if (t == 0) out[0] = p + b2[0];
    }
}

extern "C" void kernel_launch(void* const* d_in, const int* in_sizes, int n_in,
                              void* d_out, int out_size, void* d_ws, size_t ws_size,
                              hipStream_t stream) {
    const float* x_fm = (const float*)d_in[0];
    const float* x_sm = (const float*)d_in[1];
    const float* period_vol = (const float*)d_in[2];
    const float* gf = (const float*)d_in[3];
    const float* pe_table = (const float*)d_in[4];
    const int* qoq_src = (const int*)d_in[5];
    const int* qoq_dst = (const int*)d_in[6];
    const int* bp_src = (const int*)d_in[7];
    const int* bp_dst = (const int*)d_in[8];
    const int* cp_src = (const int*)d_in[9];
    const int* cp_dst = (const int*)d_in[10];
    const int* cd_src = (const int*)d_in[11];
    const int* cd_dst = (const int*)d_in[12];
    const int* rb_src = (const int*)d_in[13];
    const int* rb_dst = (const int*)d_in[14];
    const float* qoq_Wl = (const float*)d_in[15];
    const float* qoq_bl = (const float*)d_in[16];
    const float* qoq_Wr = (const float*)d_in[17];
    const float* bp_Wl = (const float*)d_in[18];
    const float* bp_bl = (const float*)d_in[19];
    const float* bp_Wr = (const float*)d_in[20];
    const float* cp_Wl = (const float*)d_in[21];
    const float* cp_bl = (const float*)d_in[22];
    const float* cp_Wr = (const float*)d_in[23];
    const float* cd_Wl = (const float*)d_in[24];
    const float* cd_bl = (const float*)d_in[25];
    const float* cd_Wr = (const float*)d_in[26];
    const float* rb_Wl = (const float*)d_in[27];
    const float* rb_bl = (const float*)d_in[28];
    const float* rb_Wr = (const float*)d_in[29];
    const float* ln_fm_g = (const float*)d_in[30];
    const float* ln_fm_b = (const float*)d_in[31];
    const float* ln_tp_g = (const float*)d_in[32];
    const float* ln_tp_b = (const float*)d_in[33];
    const float* ln_sm_g = (const float*)d_in[34];
    const float* ln_sm_b = (const float*)d_in[35];
    const float* head_W1 = (const float*)d_in[36];
    const float* head_b1 = (const float*)d_in[37];
    const float* head_W2 = (const float*)d_in[38];
    const float* head_b2 = (const float*)d_in[39];

    // workspace (4-byte words); zero region: bucket cursors + colsum
    unsigned* wsu = (unsigned*)d_ws;
    size_t off = 0;
    int* bwork = (int*)(wsu + off); off += NBUCK;
    float* colsum = (float*)(wsu + off); off += 384;
    size_t zero_words = off;
    unsigned* pairs = wsu + off; off += PAIRS_CAP;
    int* so_all = (int*)(wsu + off); off += PAIRS_CAP;
    int* el_beg = (int*)(wsu + off); off += NTOT;
    int* el_end = (int*)(wsu + off); off += NTOT;
    unsigned* mean_qoq = wsu + off; off += (size_t)N_FM * 32;
    unsigned* mean_cp  = wsu + off; off += (size_t)N_FM * 16;
    unsigned* mean_rb  = wsu + off; off += (size_t)N_FM * 16;
    unsigned* mean_bp  = wsu + off; off += (size_t)N_TP * 32;
    unsigned* mean_cd  = wsu + off; off += (size_t)N_SM * 16;
    unsigned* pe_f     = wsu + off; off += (size_t)N_TP * 16;
    unsigned* x_fm_f   = wsu + off; off += (size_t)N_FM * 32;
    unsigned* x_sm_f   = wsu + off; off += (size_t)N_SM * 16;
    unsigned* wf_fm    = wsu + off; off += 96 * HID;
    unsigned* wf_tp    = wsu + off; off += 48 * HID;
    unsigned* wf_sm    = wsu + off; off += 32 * HID;

    hipMemsetAsync(d_ws, 0, zero_words * 4, stream);

    pack_all<<<(R11 + 255) / 256, 256, 0, stream>>>(
        x_fm, x_sm, pe_table, period_vol, qoq_Wl, cp_Wl, rb_Wl, qoq_Wr, cp_Wr, rb_Wr,
        bp_Wl, bp_Wr, cd_Wl, cd_Wr, x_fm_f, x_sm_f, pe_f, wf_fm, wf_tp, wf_sm);

    EdgePtrs EP{qoq_src, qoq_dst, cp_src, cp_dst, rb_src, rb_dst, bp_src, bp_dst, cd_src, cd_dst};

    bin_kernel<<<NCHUNK, 256, 0, stream>>>(EP, bwork, pairs);
    esort<<<NBUCK, 256, 0, stream>>>(bwork, pairs, so_all, el_beg, el_end);
    gather_all<<<(G5 + 255) / 256, 256, 0, stream>>>(el_beg, el_end, so_all, x_fm_f, pe_f,
                                                     mean_qoq, mean_cp, mean_rb, mean_bp, mean_cd);

    fm_rows2<<<2048, 128, 0, stream>>>(mean_qoq, mean_cp, mean_rb, x_fm_f, wf_fm,
                                       qoq_bl, cp_bl, rb_bl, ln_fm_g, ln_fm_b, colsum);
    rows2<32, 16><<<N_TP / TR, 128, 0, stream>>>(N_TP / TR, mean_bp, pe_f, wf_tp,
                                                 bp_bl, ln_tp_g, ln_tp_b, colsum + 128);
    rows2<16, 16><<<2048, 128, 0, stream>>>(N_SM / TR, mean_cd, x_sm_f, wf_sm,
                                            cd_bl, ln_sm_g, ln_sm_b, colsum + 256);

    head_kernel<<<1, 512, 0, stream>>>(colsum, gf, head_W1, head_b1, head_W2, head_b2,
                                       (float*)d_out);
}